// Round 1
// baseline (1648.915 us; speedup 1.0000x reference)
//
#include <hip/hip_runtime.h>

// 2-layer GCN, restructured as:
//   deg[i]   = in-degree + 1 (self loop);  dinv = rsqrt(deg)
//   agg[i]   = sum_{e: dst=i} dinv[src]*dinv[i]*x[src]          (128-dim scatter)
//   z[i]     = relu((agg[i] + dinv[i]^2*x[i]) @ W1 + b1) @ W2   (fused, h never materialized)
//   out[i]   = sum_{e: dst=i} dinv[src]*dinv[i]*z[src] + dinv[i]^2*z[i] + b2

#define N_NODES 50000
#define N_EDGES 800000
#define D_FEAT  128
#define D_HID   500

__global__ __launch_bounds__(256) void k_deg(const int* __restrict__ dst,
                                             int* __restrict__ deg) {
    int e = blockIdx.x * 256 + threadIdx.x;
    if (e < N_EDGES) atomicAdd(&deg[dst[e]], 1);
}

__global__ __launch_bounds__(256) void k_dinv(const int* __restrict__ deg,
                                              float* __restrict__ dinv) {
    int i = blockIdx.x * 256 + threadIdx.x;
    if (i < N_NODES) dinv[i] = rsqrtf((float)(deg[i] + 1));  // +1 = self loop
}

// 32 lanes per edge, float4 per lane (128 floats/row). Atomic scatter into agg[dst].
__global__ __launch_bounds__(256) void k_scatter_x(const float* __restrict__ x,
                                                   const int* __restrict__ src,
                                                   const int* __restrict__ dst,
                                                   const float* __restrict__ dinv,
                                                   float* __restrict__ agg) {
    int e = blockIdx.x * 8 + (threadIdx.x >> 5);
    int lane = threadIdx.x & 31;
    if (e >= N_EDGES) return;
    int s = src[e], d = dst[e];
    float norm = dinv[s] * dinv[d];
    float4 v = ((const float4*)x)[(size_t)s * 32 + lane];
    float* o = agg + (size_t)d * D_FEAT + lane * 4;
    atomicAdd(o + 0, v.x * norm);
    atomicAdd(o + 1, v.y * norm);
    atomicAdd(o + 2, v.z * norm);
    atomicAdd(o + 3, v.w * norm);
}

// Fused: per 16-node tile, A = agg + dinv^2*x in LDS; each thread owns 2 of 500
// hidden columns for all 16 nodes; z[i] = sum_j relu(A_i.W1_j + b1_j)*W2_j.
__global__ __launch_bounds__(256) void k_fused_mlp(const float* __restrict__ agg,
                                                   const float* __restrict__ x,
                                                   const float* __restrict__ dinv,
                                                   const float* __restrict__ W1,
                                                   const float* __restrict__ b1,
                                                   const float* __restrict__ W2,
                                                   float* __restrict__ z) {
    __shared__ float A[16][128];
    __shared__ float red[4][16];
    const int t = threadIdx.x;
    const int node0 = blockIdx.x * 16;   // 50000 = 16 * 3125, no remainder

    // Stage A tile (with fused self-loop term): 512 float4 over 256 threads.
    for (int i = t; i < 16 * 32; i += 256) {
        int n = i >> 5;
        int c = i & 31;
        int node = node0 + n;
        float di = dinv[node];
        float d2 = di * di;
        float4 av = ((const float4*)agg)[(size_t)node * 32 + c];
        float4 xv = ((const float4*)x)[(size_t)node * 32 + c];
        av.x += d2 * xv.x; av.y += d2 * xv.y;
        av.z += d2 * xv.z; av.w += d2 * xv.w;
        *(float4*)&A[n][c * 4] = av;
    }
    __syncthreads();

    const int  j0   = t;                       // columns 0..255
    const bool has1 = (t < D_HID - 256);       // columns 256..499
    const int  j1   = has1 ? (256 + t) : (D_HID - 1);  // clamp keeps loads in-bounds

    float acc0[16], acc1[16], zp[16];
    const float bb0 = b1[j0];
    const float bb1 = b1[j1];
#pragma unroll
    for (int n = 0; n < 16; n++) { acc0[n] = bb0; acc1[n] = bb1; }

#pragma unroll 2
    for (int k = 0; k < D_FEAT; k += 4) {
        float w0[4], w1[4];
#pragma unroll
        for (int kk = 0; kk < 4; kk++) {
            w0[kk] = W1[(k + kk) * D_HID + j0];   // coalesced across threads
            w1[kk] = W1[(k + kk) * D_HID + j1];
        }
#pragma unroll
        for (int n = 0; n < 16; n++) {
            float4 a = *(const float4*)&A[n][k];  // LDS broadcast (all threads same addr)
            acc0[n] += a.x * w0[0] + a.y * w0[1] + a.z * w0[2] + a.w * w0[3];
            acc1[n] += a.x * w1[0] + a.y * w1[1] + a.z * w1[2] + a.w * w1[3];
        }
    }

    const float w2_0 = W2[j0];
    const float w2_1 = has1 ? W2[j1] : 0.f;      // zero kills the clamped duplicate column
#pragma unroll
    for (int n = 0; n < 16; n++) {
        zp[n] = fmaxf(acc0[n], 0.f) * w2_0 + fmaxf(acc1[n], 0.f) * w2_1;
    }

    // Reduce 256 partials per node: wave64 shuffle tree, then 4-way LDS combine.
#pragma unroll
    for (int n = 0; n < 16; n++) {
        float v = zp[n];
        v += __shfl_down(v, 32);
        v += __shfl_down(v, 16);
        v += __shfl_down(v, 8);
        v += __shfl_down(v, 4);
        v += __shfl_down(v, 2);
        v += __shfl_down(v, 1);
        zp[n] = v;
    }
    const int wv = t >> 6, ln = t & 63;
    if (ln == 0) {
#pragma unroll
        for (int n = 0; n < 16; n++) red[wv][n] = zp[n];
    }
    __syncthreads();
    if (t < 16) {
        z[node0 + t] = red[0][t] + red[1][t] + red[2][t] + red[3][t];
    }
}

__global__ __launch_bounds__(256) void k_scatter_z(const int* __restrict__ src,
                                                   const int* __restrict__ dst,
                                                   const float* __restrict__ dinv,
                                                   const float* __restrict__ z,
                                                   float* __restrict__ out) {
    int e = blockIdx.x * 256 + threadIdx.x;
    if (e < N_EDGES) {
        int s = src[e], d = dst[e];
        atomicAdd(&out[d], dinv[s] * dinv[d] * z[s]);
    }
}

__global__ __launch_bounds__(256) void k_finalize(const float* __restrict__ dinv,
                                                  const float* __restrict__ z,
                                                  const float* __restrict__ b2,
                                                  float* __restrict__ out) {
    int i = blockIdx.x * 256 + threadIdx.x;
    if (i < N_NODES) out[i] += dinv[i] * dinv[i] * z[i] + b2[0];
}

extern "C" void kernel_launch(void* const* d_in, const int* in_sizes, int n_in,
                              void* d_out, int out_size, void* d_ws, size_t ws_size,
                              hipStream_t stream) {
    const float* x  = (const float*)d_in[0];
    const int*   ei = (const int*)d_in[1];     // [2, E]: row 0 = src, row 1 = dst
    const float* W1 = (const float*)d_in[2];   // [128, 500] row-major
    const float* b1 = (const float*)d_in[3];
    const float* W2 = (const float*)d_in[4];   // [500, 1]
    const float* b2 = (const float*)d_in[5];
    float* out = (float*)d_out;                // [50000] fp32

    const int* src = ei;
    const int* dst = ei + N_EDGES;

    // Workspace layout (ws re-poisoned 0xAA each call -> memset what we accumulate into)
    float* agg  = (float*)d_ws;                          // N_NODES*128 f32 = 25.6 MB
    float* dinv = agg + (size_t)N_NODES * D_FEAT;        // N_NODES
    float* z    = dinv + N_NODES;                        // N_NODES
    int*   deg  = (int*)(z + N_NODES);                   // N_NODES

    hipMemsetAsync(agg, 0, (size_t)N_NODES * D_FEAT * sizeof(float), stream);
    hipMemsetAsync(deg, 0, (size_t)N_NODES * sizeof(int), stream);
    hipMemsetAsync(out, 0, (size_t)N_NODES * sizeof(float), stream);

    k_deg      <<<(N_EDGES + 255) / 256, 256, 0, stream>>>(dst, deg);
    k_dinv     <<<(N_NODES + 255) / 256, 256, 0, stream>>>(deg, dinv);
    k_scatter_x<<<N_EDGES / 8,            256, 0, stream>>>(x, src, dst, dinv, agg);
    k_fused_mlp<<<N_NODES / 16,           256, 0, stream>>>(agg, x, dinv, W1, b1, W2, z);
    k_scatter_z<<<(N_EDGES + 255) / 256,  256, 0, stream>>>(src, dst, dinv, z, out);
    k_finalize <<<(N_NODES + 255) / 256,  256, 0, stream>>>(dinv, z, b2, out);
}

// Round 2
// 368.048 us; speedup vs baseline: 4.4802x; 4.4802x over previous
//
#include <hip/hip_runtime.h>

// 2-layer GCN, CSR-gather formulation (atomic-free feature aggregation):
//   deg[i]  = in-degree;  dinv = rsqrt(deg+1)                  (+1 = self loop)
//   CSR: row_ptr/csr_src via histogram -> block scan -> fill
//   agg[i]  = dinv[i]*sum_{s in N(i)} dinv[s]*x[s] + dinv[i]^2*x[i]   (gather, self loop folded)
//   z[i]    = relu(agg[i] @ W1 + b1) @ W2 ;  zd[i] = dinv[i]*z[i]
//   out[i]  = dinv[i]*sum_{s in N(i)} zd[s] + dinv[i]*zd[i] + b2      (scalar gather)

#define N_NODES 50000
#define N_EDGES 800000
#define D_FEAT  128
#define D_HID   500
#define NBLK    196          // ceil(50000/256)

__global__ __launch_bounds__(256) void k_deg(const int* __restrict__ dst,
                                             int* __restrict__ deg) {
    int e = blockIdx.x * 256 + threadIdx.x;
    if (e < N_EDGES) atomicAdd(&deg[dst[e]], 1);
}

// Exclusive scan of deg -> row_ptr, in 3 passes (per-block, block sums, add offsets).
__global__ __launch_bounds__(256) void k_scan1(const int* __restrict__ deg,
                                               int* __restrict__ row_ptr,
                                               int* __restrict__ bsum) {
    __shared__ int ps[256];
    int tid = threadIdx.x;
    int i = blockIdx.x * 256 + tid;
    int v = (i < N_NODES) ? deg[i] : 0;
    ps[tid] = v;
    __syncthreads();
    for (int off = 1; off < 256; off <<= 1) {
        int t = (tid >= off) ? ps[tid - off] : 0;
        __syncthreads();
        ps[tid] += t;
        __syncthreads();
    }
    if (i < N_NODES) row_ptr[i] = ps[tid] - v;   // exclusive within block
    if (tid == 255) bsum[blockIdx.x] = ps[255];
}

__global__ __launch_bounds__(256) void k_scan2(const int* __restrict__ bsum,
                                               int* __restrict__ boff) {
    __shared__ int ps[256];
    int tid = threadIdx.x;
    int v = (tid < NBLK) ? bsum[tid] : 0;
    ps[tid] = v;
    __syncthreads();
    for (int off = 1; off < 256; off <<= 1) {
        int t = (tid >= off) ? ps[tid - off] : 0;
        __syncthreads();
        ps[tid] += t;
        __syncthreads();
    }
    boff[tid] = ps[tid] - v;
}

__global__ __launch_bounds__(256) void k_scan3(const int* __restrict__ deg,
                                               const int* __restrict__ boff,
                                               int* __restrict__ row_ptr,
                                               float* __restrict__ dinv) {
    int i = blockIdx.x * 256 + threadIdx.x;
    if (i < N_NODES) {
        row_ptr[i] += boff[blockIdx.x];
        dinv[i] = rsqrtf((float)(deg[i] + 1));
    }
    if (i == 0) row_ptr[N_NODES] = N_EDGES;
}

__global__ __launch_bounds__(256) void k_fill(const int* __restrict__ src,
                                              const int* __restrict__ dst,
                                              const int* __restrict__ row_ptr,
                                              int* __restrict__ cursor,
                                              int* __restrict__ csr) {
    int e = blockIdx.x * 256 + threadIdx.x;
    if (e < N_EDGES) {
        int d = dst[e];
        int pos = row_ptr[d] + atomicAdd(&cursor[d], 1);
        csr[pos] = src[e];
    }
}

// One wave per node; lane owns a float2 column slice (64*2 = 128 floats).
// agg written once per node; self-loop folded in.
__global__ __launch_bounds__(256) void k_gather_x(const float* __restrict__ x,
                                                  const int* __restrict__ csr,
                                                  const int* __restrict__ row_ptr,
                                                  const float* __restrict__ dinv,
                                                  float* __restrict__ agg) {
    const int node = blockIdx.x * 4 + (threadIdx.x >> 6);
    const int lane = threadIdx.x & 63;
    const float2* __restrict__ x2 = (const float2*)x;

    int e = row_ptr[node];
    const int end = row_ptr[node + 1];
    float ax = 0.f, ay = 0.f;

    for (; e + 3 < end; e += 4) {
        int s0 = csr[e], s1 = csr[e + 1], s2 = csr[e + 2], s3 = csr[e + 3];
        float w0 = dinv[s0], w1 = dinv[s1], w2 = dinv[s2], w3 = dinv[s3];
        float2 v0 = x2[(size_t)s0 * 64 + lane];
        float2 v1 = x2[(size_t)s1 * 64 + lane];
        float2 v2 = x2[(size_t)s2 * 64 + lane];
        float2 v3 = x2[(size_t)s3 * 64 + lane];
        ax += w0 * v0.x + w1 * v1.x + w2 * v2.x + w3 * v3.x;
        ay += w0 * v0.y + w1 * v1.y + w2 * v2.y + w3 * v3.y;
    }
    for (; e < end; e++) {
        int s = csr[e];
        float w = dinv[s];
        float2 v = x2[(size_t)s * 64 + lane];
        ax += w * v.x;
        ay += w * v.y;
    }

    const float di = dinv[node];
    float2 xv = x2[(size_t)node * 64 + lane];
    float2 o;
    o.x = di * ax + di * di * xv.x;
    o.y = di * ay + di * di * xv.y;
    ((float2*)agg)[(size_t)node * 64 + lane] = o;
}

// Fused GEMM1+bias+ReLU+dot(W2): per 16-node tile; thread owns 2 of 500 hidden
// columns for all 16 nodes. Emits zd = dinv*z (all later consumers need only zd).
__global__ __launch_bounds__(256) void k_fused_mlp(const float* __restrict__ agg,
                                                   const float* __restrict__ dinv,
                                                   const float* __restrict__ W1,
                                                   const float* __restrict__ b1,
                                                   const float* __restrict__ W2,
                                                   float* __restrict__ zd) {
    __shared__ float A[16][128];
    __shared__ float red[4][16];
    const int t = threadIdx.x;
    const int node0 = blockIdx.x * 16;   // 50000 = 16 * 3125

    for (int i = t; i < 16 * 32; i += 256) {
        int n = i >> 5;
        int c = i & 31;
        *(float4*)&A[n][c * 4] = ((const float4*)agg)[(size_t)(node0 + n) * 32 + c];
    }
    __syncthreads();

    const int  j0   = t;
    const bool has1 = (t < D_HID - 256);
    const int  j1   = has1 ? (256 + t) : (D_HID - 1);

    float acc0[16], acc1[16], zp[16];
    const float bb0 = b1[j0];
    const float bb1 = b1[j1];
#pragma unroll
    for (int n = 0; n < 16; n++) { acc0[n] = bb0; acc1[n] = bb1; }

#pragma unroll 2
    for (int k = 0; k < D_FEAT; k += 4) {
        float w0[4], w1[4];
#pragma unroll
        for (int kk = 0; kk < 4; kk++) {
            w0[kk] = W1[(k + kk) * D_HID + j0];
            w1[kk] = W1[(k + kk) * D_HID + j1];
        }
#pragma unroll
        for (int n = 0; n < 16; n++) {
            float4 a = *(const float4*)&A[n][k];
            acc0[n] += a.x * w0[0] + a.y * w0[1] + a.z * w0[2] + a.w * w0[3];
            acc1[n] += a.x * w1[0] + a.y * w1[1] + a.z * w1[2] + a.w * w1[3];
        }
    }

    const float w2_0 = W2[j0];
    const float w2_1 = has1 ? W2[j1] : 0.f;
#pragma unroll
    for (int n = 0; n < 16; n++) {
        zp[n] = fmaxf(acc0[n], 0.f) * w2_0 + fmaxf(acc1[n], 0.f) * w2_1;
    }

#pragma unroll
    for (int n = 0; n < 16; n++) {
        float v = zp[n];
        v += __shfl_down(v, 32);
        v += __shfl_down(v, 16);
        v += __shfl_down(v, 8);
        v += __shfl_down(v, 4);
        v += __shfl_down(v, 2);
        v += __shfl_down(v, 1);
        zp[n] = v;
    }
    const int wv = t >> 6, ln = t & 63;
    if (ln == 0) {
#pragma unroll
        for (int n = 0; n < 16; n++) red[wv][n] = zp[n];
    }
    __syncthreads();
    if (t < 16) {
        int node = node0 + t;
        float zz = red[0][t] + red[1][t] + red[2][t] + red[3][t];
        zd[node] = dinv[node] * zz;
    }
}

// Scalar gather for layer 2: zd is 200 KB -> L2-resident.
__global__ __launch_bounds__(256) void k_gather_z(const int* __restrict__ csr,
                                                  const int* __restrict__ row_ptr,
                                                  const float* __restrict__ dinv,
                                                  const float* __restrict__ zd,
                                                  const float* __restrict__ b2,
                                                  float* __restrict__ out) {
    int i = blockIdx.x * 256 + threadIdx.x;
    if (i >= N_NODES) return;
    int e = row_ptr[i];
    const int end = row_ptr[i + 1];
    float a0 = 0.f, a1 = 0.f;
    for (; e + 1 < end; e += 2) {
        a0 += zd[csr[e]];
        a1 += zd[csr[e + 1]];
    }
    if (e < end) a0 += zd[csr[e]];
    float di = dinv[i];
    out[i] = di * (a0 + a1) + di * zd[i] + b2[0];
}

extern "C" void kernel_launch(void* const* d_in, const int* in_sizes, int n_in,
                              void* d_out, int out_size, void* d_ws, size_t ws_size,
                              hipStream_t stream) {
    const float* x  = (const float*)d_in[0];
    const int*   ei = (const int*)d_in[1];     // [2, E]: row 0 = src, row 1 = dst
    const float* W1 = (const float*)d_in[2];
    const float* b1 = (const float*)d_in[3];
    const float* W2 = (const float*)d_in[4];
    const float* b2 = (const float*)d_in[5];
    float* out = (float*)d_out;

    const int* src = ei;
    const int* dst = ei + N_EDGES;

    // Workspace layout (~30 MB)
    float* agg  = (float*)d_ws;                          // 6,400,000 f
    float* dinv = agg + (size_t)N_NODES * D_FEAT;        // 50000
    float* zd   = dinv + N_NODES;                        // 50000
    int* deg     = (int*)(zd + N_NODES);                 // 50000
    int* row_ptr = deg + N_NODES;                        // 50001
    int* cursor  = row_ptr + N_NODES + 1;                // 50000
    int* bsum    = cursor + N_NODES;                     // 256
    int* boff    = bsum + 256;                           // 256
    int* csr     = boff + 256;                           // 800000

    hipMemsetAsync(deg, 0, N_NODES * sizeof(int), stream);
    hipMemsetAsync(cursor, 0, N_NODES * sizeof(int), stream);

    k_deg      <<<(N_EDGES + 255) / 256, 256, 0, stream>>>(dst, deg);
    k_scan1    <<<NBLK, 256, 0, stream>>>(deg, row_ptr, bsum);
    k_scan2    <<<1,    256, 0, stream>>>(bsum, boff);
    k_scan3    <<<NBLK, 256, 0, stream>>>(deg, boff, row_ptr, dinv);
    k_fill     <<<(N_EDGES + 255) / 256, 256, 0, stream>>>(src, dst, row_ptr, cursor, csr);
    k_gather_x <<<N_NODES / 4,  256, 0, stream>>>(x, csr, row_ptr, dinv, agg);
    k_fused_mlp<<<N_NODES / 16, 256, 0, stream>>>(agg, dinv, W1, b1, W2, zd);
    k_gather_z <<<(N_NODES + 255) / 256, 256, 0, stream>>>(csr, row_ptr, dinv, zd, b2, out);
}

// Round 3
// 318.000 us; speedup vs baseline: 5.1853x; 1.1574x over previous
//
#include <hip/hip_runtime.h>

// 2-layer GCN, CSR-gather + fully fused layer-1:
//   k_gcn1 (one block = 16 nodes):
//     phase 1: gather A[n] = dinv[n]*sum_{s in N(n)} dinv[s]*x[s] + dinv[n]^2*x[n]  -> LDS
//     phase 2: zd[n] = dinv[n] * ( relu(A[n] @ W1 + b1) @ W2 )
//   k_gather_z: out[i] = dinv[i]*sum_{s in N(i)} zd[s] + dinv[i]*zd[i] + b2

#define N_NODES 50000
#define N_EDGES 800000
#define D_FEAT  128
#define D_HID   500
#define NBLK    196          // ceil(50000/256)

__global__ __launch_bounds__(256) void k_deg(const int* __restrict__ dst,
                                             int* __restrict__ deg) {
    int e = blockIdx.x * 256 + threadIdx.x;
    if (e < N_EDGES) atomicAdd(&deg[dst[e]], 1);
}

__global__ __launch_bounds__(256) void k_scan1(const int* __restrict__ deg,
                                               int* __restrict__ row_ptr,
                                               int* __restrict__ bsum) {
    __shared__ int ps[256];
    int tid = threadIdx.x;
    int i = blockIdx.x * 256 + tid;
    int v = (i < N_NODES) ? deg[i] : 0;
    ps[tid] = v;
    __syncthreads();
    for (int off = 1; off < 256; off <<= 1) {
        int t = (tid >= off) ? ps[tid - off] : 0;
        __syncthreads();
        ps[tid] += t;
        __syncthreads();
    }
    if (i < N_NODES) row_ptr[i] = ps[tid] - v;
    if (tid == 255) bsum[blockIdx.x] = ps[255];
}

__global__ __launch_bounds__(256) void k_scan2(const int* __restrict__ bsum,
                                               int* __restrict__ boff) {
    __shared__ int ps[256];
    int tid = threadIdx.x;
    int v = (tid < NBLK) ? bsum[tid] : 0;
    ps[tid] = v;
    __syncthreads();
    for (int off = 1; off < 256; off <<= 1) {
        int t = (tid >= off) ? ps[tid - off] : 0;
        __syncthreads();
        ps[tid] += t;
        __syncthreads();
    }
    boff[tid] = ps[tid] - v;
}

__global__ __launch_bounds__(256) void k_scan3(const int* __restrict__ deg,
                                               const int* __restrict__ boff,
                                               int* __restrict__ row_ptr,
                                               float* __restrict__ dinv) {
    int i = blockIdx.x * 256 + threadIdx.x;
    if (i < N_NODES) {
        row_ptr[i] += boff[blockIdx.x];
        dinv[i] = rsqrtf((float)(deg[i] + 1));
    }
    if (i == 0) row_ptr[N_NODES] = N_EDGES;
}

__global__ __launch_bounds__(256) void k_fill(const int* __restrict__ src,
                                              const int* __restrict__ dst,
                                              const int* __restrict__ row_ptr,
                                              int* __restrict__ cursor,
                                              int* __restrict__ csr) {
    int e = blockIdx.x * 256 + threadIdx.x;
    if (e < N_EDGES) {
        int d = dst[e];
        int pos = row_ptr[d] + atomicAdd(&cursor[d], 1);
        csr[pos] = src[e];
    }
}

// Fused gather + MLP. Block = 16 nodes. Phase 1: each of 4 waves gathers 4
// nodes' aggregated features (lane owns 2 adjacent cols) straight into LDS.
// Phase 2: thread t owns hidden cols {2t, 2t+1} (t<250); pure-fmaf inner loop.
__global__ __launch_bounds__(256, 4) void k_gcn1(const float* __restrict__ x,
                                                 const int* __restrict__ csr,
                                                 const int* __restrict__ row_ptr,
                                                 const float* __restrict__ dinv,
                                                 const float* __restrict__ W1,
                                                 const float* __restrict__ b1,
                                                 const float* __restrict__ W2,
                                                 float* __restrict__ zd) {
    __shared__ float A[16][128];
    __shared__ float red[4][16];
    const int t = threadIdx.x;
    const int node0 = blockIdx.x * 16;      // 50000 = 16 * 3125
    const int wv = t >> 6, lane = t & 63;
    const float2* __restrict__ x2 = (const float2*)x;

    // ---- Phase 1: gather 4 nodes per wave, float2 column slice per lane ----
    for (int nn = 0; nn < 4; nn++) {
        const int n = wv * 4 + nn;
        const int node = node0 + n;
        int e = row_ptr[node];
        const int end = row_ptr[node + 1];
        float ax = 0.f, ay = 0.f;
        for (; e + 3 < end; e += 4) {
            int s0 = csr[e], s1 = csr[e + 1], s2 = csr[e + 2], s3 = csr[e + 3];
            float w0 = dinv[s0], w1 = dinv[s1], w2 = dinv[s2], w3 = dinv[s3];
            float2 v0 = x2[(size_t)s0 * 64 + lane];
            float2 v1 = x2[(size_t)s1 * 64 + lane];
            float2 v2 = x2[(size_t)s2 * 64 + lane];
            float2 v3 = x2[(size_t)s3 * 64 + lane];
            ax += w0 * v0.x + w1 * v1.x + w2 * v2.x + w3 * v3.x;
            ay += w0 * v0.y + w1 * v1.y + w2 * v2.y + w3 * v3.y;
        }
        for (; e < end; e++) {
            int s = csr[e];
            float w = dinv[s];
            float2 v = x2[(size_t)s * 64 + lane];
            ax += w * v.x;
            ay += w * v.y;
        }
        const float di = dinv[node];
        float2 xv = x2[(size_t)node * 64 + lane];
        float2 o;
        o.x = di * ax + di * di * xv.x;
        o.y = di * ay + di * di * xv.y;
        *(float2*)&A[n][lane * 2] = o;      // stride-1 float2: 2-way bank alias = free
    }
    __syncthreads();

    // ---- Phase 2: MLP. cols j0=2t, j1=2t+1 (clamped for t>=250, w2 zeroed) ----
    const bool active = (t < D_HID / 2);            // 250 threads carry real cols
    const int tc = active ? t : (D_HID / 2 - 1);
    const float* __restrict__ w1p = W1 + 2 * tc;

    float acc0[16], acc1[16], zp[16];
    {
        float2 bb = *(const float2*)(b1 + 2 * tc);
#pragma unroll
        for (int n = 0; n < 16; n++) { acc0[n] = bb.x; acc1[n] = bb.y; }
    }

    for (int k = 0; k < D_FEAT; k += 8) {
        float2 wvv[8];
#pragma unroll
        for (int kk = 0; kk < 8; kk++)
            wvv[kk] = *(const float2*)(w1p + (size_t)(k + kk) * D_HID);
#pragma unroll
        for (int n = 0; n < 16; n++) {
            float4 a0 = *(const float4*)&A[n][k];
            float4 a1 = *(const float4*)&A[n][k + 4];
            acc0[n] = fmaf(a0.x, wvv[0].x, acc0[n]);
            acc1[n] = fmaf(a0.x, wvv[0].y, acc1[n]);
            acc0[n] = fmaf(a0.y, wvv[1].x, acc0[n]);
            acc1[n] = fmaf(a0.y, wvv[1].y, acc1[n]);
            acc0[n] = fmaf(a0.z, wvv[2].x, acc0[n]);
            acc1[n] = fmaf(a0.z, wvv[2].y, acc1[n]);
            acc0[n] = fmaf(a0.w, wvv[3].x, acc0[n]);
            acc1[n] = fmaf(a0.w, wvv[3].y, acc1[n]);
            acc0[n] = fmaf(a1.x, wvv[4].x, acc0[n]);
            acc1[n] = fmaf(a1.x, wvv[4].y, acc1[n]);
            acc0[n] = fmaf(a1.y, wvv[5].x, acc0[n]);
            acc1[n] = fmaf(a1.y, wvv[5].y, acc1[n]);
            acc0[n] = fmaf(a1.z, wvv[6].x, acc0[n]);
            acc1[n] = fmaf(a1.z, wvv[6].y, acc1[n]);
            acc0[n] = fmaf(a1.w, wvv[7].x, acc0[n]);
            acc1[n] = fmaf(a1.w, wvv[7].y, acc1[n]);
        }
    }

    float2 w2v;
    if (active) w2v = *(const float2*)(W2 + 2 * tc);
    else        w2v = make_float2(0.f, 0.f);
#pragma unroll
    for (int n = 0; n < 16; n++) {
        zp[n] = fmaxf(acc0[n], 0.f) * w2v.x + fmaxf(acc1[n], 0.f) * w2v.y;
    }

#pragma unroll
    for (int n = 0; n < 16; n++) {
        float v = zp[n];
        v += __shfl_down(v, 32);
        v += __shfl_down(v, 16);
        v += __shfl_down(v, 8);
        v += __shfl_down(v, 4);
        v += __shfl_down(v, 2);
        v += __shfl_down(v, 1);
        zp[n] = v;
    }
    if ((t & 63) == 0) {
#pragma unroll
        for (int n = 0; n < 16; n++) red[wv][n] = zp[n];
    }
    __syncthreads();
    if (t < 16) {
        int node = node0 + t;
        float zz = red[0][t] + red[1][t] + red[2][t] + red[3][t];
        zd[node] = dinv[node] * zz;
    }
}

__global__ __launch_bounds__(256) void k_gather_z(const int* __restrict__ csr,
                                                  const int* __restrict__ row_ptr,
                                                  const float* __restrict__ dinv,
                                                  const float* __restrict__ zd,
                                                  const float* __restrict__ b2,
                                                  float* __restrict__ out) {
    int i = blockIdx.x * 256 + threadIdx.x;
    if (i >= N_NODES) return;
    int e = row_ptr[i];
    const int end = row_ptr[i + 1];
    float a0 = 0.f, a1 = 0.f, a2 = 0.f, a3 = 0.f;
    for (; e + 3 < end; e += 4) {
        a0 += zd[csr[e]];
        a1 += zd[csr[e + 1]];
        a2 += zd[csr[e + 2]];
        a3 += zd[csr[e + 3]];
    }
    for (; e < end; e++) a0 += zd[csr[e]];
    float di = dinv[i];
    out[i] = di * ((a0 + a1) + (a2 + a3)) + di * zd[i] + b2[0];
}

extern "C" void kernel_launch(void* const* d_in, const int* in_sizes, int n_in,
                              void* d_out, int out_size, void* d_ws, size_t ws_size,
                              hipStream_t stream) {
    const float* x  = (const float*)d_in[0];
    const int*   ei = (const int*)d_in[1];     // [2, E]: row 0 = src, row 1 = dst
    const float* W1 = (const float*)d_in[2];
    const float* b1 = (const float*)d_in[3];
    const float* W2 = (const float*)d_in[4];
    const float* b2 = (const float*)d_in[5];
    float* out = (float*)d_out;

    const int* src = ei;
    const int* dst = ei + N_EDGES;

    // Workspace (~4.2 MB)
    float* dinv  = (float*)d_ws;               // 50000
    float* zd    = dinv + N_NODES;             // 50000
    int* deg     = (int*)(zd + N_NODES);       // 50000
    int* row_ptr = deg + N_NODES;              // 50001
    int* cursor  = row_ptr + N_NODES + 1;      // 50000
    int* bsum    = cursor + N_NODES;           // 256
    int* boff    = bsum + 256;                 // 256
    int* csr     = boff + 256;                 // 800000

    hipMemsetAsync(deg, 0, N_NODES * sizeof(int), stream);
    hipMemsetAsync(cursor, 0, N_NODES * sizeof(int), stream);

    k_deg     <<<(N_EDGES + 255) / 256, 256, 0, stream>>>(dst, deg);
    k_scan1   <<<NBLK, 256, 0, stream>>>(deg, row_ptr, bsum);
    k_scan2   <<<1,    256, 0, stream>>>(bsum, boff);
    k_scan3   <<<NBLK, 256, 0, stream>>>(deg, boff, row_ptr, dinv);
    k_fill    <<<(N_EDGES + 255) / 256, 256, 0, stream>>>(src, dst, row_ptr, cursor, csr);
    k_gcn1    <<<N_NODES / 16, 256, 0, stream>>>(x, csr, row_ptr, dinv, W1, b1, W2, zd);
    k_gather_z<<<(N_NODES + 255) / 256, 256, 0, stream>>>(csr, row_ptr, dinv, zd, b2, out);
}

// Round 4
// 237.999 us; speedup vs baseline: 6.9282x; 1.3361x over previous
//
#include <hip/hip_runtime.h>

// 2-layer GCN, CSR-gather + bf16-MFMA fused layer-1:
//   k_pre : deg histogram | x -> bf16 | W1 -> bf16 B-fragment pack | b1/W2 pad
//   scan  : row_ptr = exclusive_scan(deg); cursor seeded = row_ptr
//   k_fill: CSR column list
//   k_gcn1: per 16-node block: gather A = D^-1/2 (A+I) D^-1/2 X  (bf16 -> LDS),
//           then zd = dinv * ( relu(A@W1 + b1) @ W2 ) via mfma_f32_16x16x32_bf16
//   k_gz  : out[i] = dinv[i]*(sum_{s in N(i)} zd[s] + zd[i]) + b2

#define N_NODES 50000
#define N_EDGES 800000
#define D_FEAT  128
#define D_HID   500
#define NTILE   32           // 512 padded hidden cols / 16
#define NBLK    196          // ceil(50000/256)

typedef __bf16 bf16x8 __attribute__((ext_vector_type(8)));
typedef float  f32x4  __attribute__((ext_vector_type(4)));

static __device__ inline unsigned int f2bf(float f) {   // fp32 -> bf16 bits, RTNE
    unsigned int u = __float_as_uint(f);
    return (u + 0x7fffu + ((u >> 16) & 1u)) >> 16;
}
static __device__ inline float bf_lo(unsigned int u) { return __uint_as_float(u << 16); }
static __device__ inline float bf_hi(unsigned int u) { return __uint_as_float(u & 0xffff0000u); }

// ---- fused preprocessing: blocks [0,3125) deg | [3125,9375) x->bf16 |
// ---- [9375,9407) W1 pack | 9407 b1/W2 pad ----
__global__ __launch_bounds__(256) void k_pre(const int* __restrict__ dst,
                                             const float* __restrict__ x,
                                             const float* __restrict__ W1,
                                             const float* __restrict__ b1,
                                             const float* __restrict__ W2,
                                             int* __restrict__ deg,
                                             uint2* __restrict__ x_bf,
                                             unsigned short* __restrict__ b_pk,
                                             float* __restrict__ b1p,
                                             float* __restrict__ w2p) {
    const int b = blockIdx.x, tid = threadIdx.x;
    if (b < 3125) {                                   // deg histogram
        int e = b * 256 + tid;
        atomicAdd(&deg[dst[e]], 1);
    } else if (b < 9375) {                            // x -> bf16 (4 elems/thread)
        int i = (b - 3125) * 256 + tid;               // i < 1,600,000
        float4 v = ((const float4*)x)[i];
        uint2 o;
        o.x = f2bf(v.x) | (f2bf(v.y) << 16);
        o.y = f2bf(v.z) | (f2bf(v.w) << 16);
        x_bf[i] = o;
    } else if (b < 9407) {                            // W1 -> B-fragment pack
        int idx  = (b - 9375) * 256 + tid;            // [0, 8192)
        int lane = idx & 63;
        int slot = idx >> 6;
        int t    = slot >> 2;                         // n-tile
        int ks   = slot & 3;                          // k-step
        int quad = lane >> 4;
        int n    = t * 16 + (lane & 15);
        unsigned int us[8];
#pragma unroll
        for (int j = 0; j < 8; j++) {
            int k = ks * 32 + quad * 8 + j;
            float v = (n < D_HID) ? W1[(size_t)k * D_HID + n] : 0.f;
            us[j] = f2bf(v);
        }
        uint4 p;
        p.x = us[0] | (us[1] << 16);
        p.y = us[2] | (us[3] << 16);
        p.z = us[4] | (us[5] << 16);
        p.w = us[6] | (us[7] << 16);
        ((uint4*)b_pk)[idx] = p;
    } else {                                          // pad b1 / W2 to 512
        for (int i = tid; i < 512; i += 256) {
            b1p[i] = (i < D_HID) ? b1[i] : 0.f;
            w2p[i] = (i < D_HID) ? W2[i] : 0.f;
        }
    }
}

__global__ __launch_bounds__(256) void k_scan1(const int* __restrict__ deg,
                                               int* __restrict__ row_ptr,
                                               int* __restrict__ bsum) {
    __shared__ int ps[256];
    int tid = threadIdx.x;
    int i = blockIdx.x * 256 + tid;
    int v = (i < N_NODES) ? deg[i] : 0;
    ps[tid] = v;
    __syncthreads();
    for (int off = 1; off < 256; off <<= 1) {
        int t = (tid >= off) ? ps[tid - off] : 0;
        __syncthreads();
        ps[tid] += t;
        __syncthreads();
    }
    if (i < N_NODES) row_ptr[i] = ps[tid] - v;
    if (tid == 255) bsum[blockIdx.x] = ps[255];
}

__global__ __launch_bounds__(256) void k_scan2(const int* __restrict__ bsum,
                                               int* __restrict__ boff) {
    __shared__ int ps[256];
    int tid = threadIdx.x;
    int v = (tid < NBLK) ? bsum[tid] : 0;
    ps[tid] = v;
    __syncthreads();
    for (int off = 1; off < 256; off <<= 1) {
        int t = (tid >= off) ? ps[tid - off] : 0;
        __syncthreads();
        ps[tid] += t;
        __syncthreads();
    }
    boff[tid] = ps[tid] - v;
}

__global__ __launch_bounds__(256) void k_scan3(const int* __restrict__ deg,
                                               const int* __restrict__ boff,
                                               int* __restrict__ row_ptr,
                                               int* __restrict__ cursor,
                                               float* __restrict__ dinv) {
    int i = blockIdx.x * 256 + threadIdx.x;
    if (i < N_NODES) {
        int r = row_ptr[i] + boff[blockIdx.x];
        row_ptr[i] = r;
        cursor[i] = r;                      // k_fill bumps this copy
        dinv[i] = rsqrtf((float)(deg[i] + 1));
    }
    if (i == 0) row_ptr[N_NODES] = N_EDGES;
}

__global__ __launch_bounds__(256) void k_fill(const int* __restrict__ src,
                                              const int* __restrict__ dst,
                                              int* __restrict__ cursor,
                                              int* __restrict__ csr) {
    int e = blockIdx.x * 256 + threadIdx.x;
    if (e < N_EDGES) {
        int pos = atomicAdd(&cursor[dst[e]], 1);
        csr[pos] = src[e];
    }
}

// Fused gather + bf16-MFMA MLP. Block = 16 nodes.
__global__ __launch_bounds__(256, 4) void k_gcn1(const uint2* __restrict__ x_bf,
                                                 const int* __restrict__ csr,
                                                 const int* __restrict__ row_ptr,
                                                 const float* __restrict__ dinv,
                                                 const unsigned short* __restrict__ b_pk,
                                                 const float* __restrict__ b1p,
                                                 const float* __restrict__ w2p,
                                                 float* __restrict__ zd) {
    __shared__ unsigned short A[16][136];   // bf16; +8 pad -> bank stride 4 (uniform)
    __shared__ float red[4][16];
    const int t = threadIdx.x;
    const int node0 = blockIdx.x * 16;      // 50000 = 16 * 3125
    const int wv = t >> 6, lane = t & 63;
    const int quad = lane >> 4, m = lane & 15;
    const unsigned int* __restrict__ xb = (const unsigned int*)x_bf;

    // ---- Phase 1: each wave gathers 4 nodes; lane owns cols {2*lane, 2*lane+1} ----
    for (int nn = 0; nn < 4; nn++) {
        const int n = wv * 4 + nn;
        const int node = node0 + n;
        int e = row_ptr[node];
        const int end = row_ptr[node + 1];
        float ax = 0.f, ay = 0.f;
        for (; e + 3 < end; e += 4) {
            int s0 = csr[e], s1 = csr[e + 1], s2 = csr[e + 2], s3 = csr[e + 3];
            float w0 = dinv[s0], w1 = dinv[s1], w2 = dinv[s2], w3 = dinv[s3];
            unsigned int u0 = xb[(size_t)s0 * 64 + lane];
            unsigned int u1 = xb[(size_t)s1 * 64 + lane];
            unsigned int u2 = xb[(size_t)s2 * 64 + lane];
            unsigned int u3 = xb[(size_t)s3 * 64 + lane];
            ax += w0 * bf_lo(u0) + w1 * bf_lo(u1) + w2 * bf_lo(u2) + w3 * bf_lo(u3);
            ay += w0 * bf_hi(u0) + w1 * bf_hi(u1) + w2 * bf_hi(u2) + w3 * bf_hi(u3);
        }
        for (; e < end; e++) {
            int s = csr[e];
            float w = dinv[s];
            unsigned int u = xb[(size_t)s * 64 + lane];
            ax += w * bf_lo(u);
            ay += w * bf_hi(u);
        }
        const float di = dinv[node];
        unsigned int su = xb[(size_t)node * 64 + lane];
        float ox = di * ax + di * di * bf_lo(su);
        float oy = di * ay + di * di * bf_hi(su);
        *(unsigned int*)&A[n][lane * 2] = f2bf(ox) | (f2bf(oy) << 16);
    }
    __syncthreads();

    // ---- Phase 2: D[16 nodes][512 cols] via 16x16x32 bf16 MFMA; wave owns 8 n-tiles ----
    bf16x8 afr[4];
#pragma unroll
    for (int ks = 0; ks < 4; ks++)
        afr[ks] = *(const bf16x8*)&A[m][ks * 32 + quad * 8];

    const bf16x8* __restrict__ bp = (const bf16x8*)b_pk;
    f32x4 acc[8];
#pragma unroll
    for (int tt = 0; tt < 8; tt++) acc[tt] = (f32x4){0.f, 0.f, 0.f, 0.f};

#pragma unroll
    for (int tt = 0; tt < 8; tt++) {
        const int tile = wv * 8 + tt;
#pragma unroll
        for (int ks = 0; ks < 4; ks++) {
            bf16x8 bfr = bp[(size_t)(tile * 4 + ks) * 64 + lane];
            acc[tt] = __builtin_amdgcn_mfma_f32_16x16x32_bf16(afr[ks], bfr, acc[tt], 0, 0, 0);
        }
    }

    // epilogue: h = D + b1; z-partial = relu(h) . W2   (C/D: col=lane&15, row=quad*4+reg)
    float zp[4] = {0.f, 0.f, 0.f, 0.f};
#pragma unroll
    for (int tt = 0; tt < 8; tt++) {
        const int c = (wv * 8 + tt) * 16 + m;
        const float b1v = b1p[c];
        const float w2v = w2p[c];
#pragma unroll
        for (int r = 0; r < 4; r++)
            zp[r] += fmaxf(acc[tt][r] + b1v, 0.f) * w2v;
    }
#pragma unroll
    for (int off = 1; off < 16; off <<= 1) {
#pragma unroll
        for (int r = 0; r < 4; r++) zp[r] += __shfl_xor(zp[r], off);
    }
    if (m == 0) {
#pragma unroll
        for (int r = 0; r < 4; r++) red[wv][quad * 4 + r] = zp[r];
    }
    __syncthreads();
    if (t < 16) {
        int node = node0 + t;
        float zz = red[0][t] + red[1][t] + red[2][t] + red[3][t];
        zd[node] = dinv[node] * zz;
    }
}

// Layer-2 scalar gather: 16 lanes per node, shuffle-reduce.
__global__ __launch_bounds__(256) void k_gz(const int* __restrict__ csr,
                                            const int* __restrict__ row_ptr,
                                            const float* __restrict__ dinv,
                                            const float* __restrict__ zd,
                                            const float* __restrict__ b2,
                                            float* __restrict__ out) {
    const int node = blockIdx.x * 16 + (threadIdx.x >> 4);
    const int l = threadIdx.x & 15;
    const int start = row_ptr[node], end = row_ptr[node + 1];
    float s = 0.f;
    for (int e = start + l; e < end; e += 16) s += zd[csr[e]];
#pragma unroll
    for (int off = 1; off < 16; off <<= 1) s += __shfl_xor(s, off);
    if (l == 0) out[node] = dinv[node] * (s + zd[node]) + b2[0];
}

extern "C" void kernel_launch(void* const* d_in, const int* in_sizes, int n_in,
                              void* d_out, int out_size, void* d_ws, size_t ws_size,
                              hipStream_t stream) {
    const float* x  = (const float*)d_in[0];
    const int*   ei = (const int*)d_in[1];     // [2, E]: row 0 = src, row 1 = dst
    const float* W1 = (const float*)d_in[2];
    const float* b1 = (const float*)d_in[3];
    const float* W2 = (const float*)d_in[4];
    const float* b2 = (const float*)d_in[5];
    float* out = (float*)d_out;

    const int* src = ei;
    const int* dst = ei + N_EDGES;

    // Workspace layout (~17.5 MB)
    uint2* x_bf          = (uint2*)d_ws;                       // 1,600,000 uint2 (12.8 MB)
    unsigned short* b_pk = (unsigned short*)(x_bf + 1600000);  // 65,536 bf16 (128 KB)
    float* b1p    = (float*)(b_pk + 65536);                    // 512
    float* w2p    = b1p + 512;                                 // 512
    float* dinv   = w2p + 512;                                 // 50000
    float* zd     = dinv + N_NODES;                            // 50000
    int* deg      = (int*)(zd + N_NODES);                      // 50000
    int* row_ptr  = deg + N_NODES;                             // 50001
    int* cursor   = row_ptr + N_NODES + 1;                     // 50000
    int* bsum     = cursor + N_NODES;                          // 256
    int* boff     = bsum + 256;                                // 256
    int* csr      = boff + 256;                                // 800000

    hipMemsetAsync(deg, 0, N_NODES * sizeof(int), stream);

    k_pre  <<<9408, 256, 0, stream>>>(dst, x, W1, b1, W2, deg, x_bf, b_pk, b1p, w2p);
    k_scan1<<<NBLK, 256, 0, stream>>>(deg, row_ptr, bsum);
    k_scan2<<<1,    256, 0, stream>>>(bsum, boff);
    k_scan3<<<NBLK, 256, 0, stream>>>(deg, boff, row_ptr, cursor, dinv);
    k_fill <<<(N_EDGES + 255) / 256, 256, 0, stream>>>(src, dst, cursor, csr);
    k_gcn1 <<<N_NODES / 16, 256, 0, stream>>>(x_bf, csr, row_ptr, dinv, b_pk, b1p, w2p, zd);
    k_gz   <<<N_NODES / 16, 256, 0, stream>>>(csr, row_ptr, dinv, zd, b2, out);
}

// Round 5
// 235.143 us; speedup vs baseline: 7.0124x; 1.0121x over previous
//
#include <hip/hip_runtime.h>

// 2-layer GCN, CSR-gather + bf16-MFMA fused layer-1:
//   k_pre : deg histogram | x -> bf16 | W1 -> bf16 B-fragment pack | b1/W2 pad
//   k_scan: single-kernel decoupled-lookback exclusive scan of deg
//           -> row_ptr, cursor (seeded), dinv                 (196 co-resident blocks)
//   k_fill: CSR column list (atomic cursor bump)
//   k_gcn1: per 16-node block: gather A = D^-1/2 (A+I) D^-1/2 X  (bf16 -> LDS),
//           4 edges/wave-instr (16 lanes x 16B per row), then
//           zd = dinv * ( relu(A@W1 + b1) @ W2 ) via mfma_f32_16x16x32_bf16
//   k_gz  : out[i] = dinv[i]*(sum_{s in N(i)} zd[s] + zd[i]) + b2

#define N_NODES 50000
#define N_EDGES 800000
#define D_FEAT  128
#define D_HID   500
#define SCANB   196          // ceil(50000/256)

typedef __bf16 bf16x8 __attribute__((ext_vector_type(8)));
typedef float  f32x4  __attribute__((ext_vector_type(4)));

static __device__ inline unsigned int f2bf(float f) {   // fp32 -> bf16 bits, RTNE
    unsigned int u = __float_as_uint(f);
    return (u + 0x7fffu + ((u >> 16) & 1u)) >> 16;
}
static __device__ inline float bf_lo(unsigned int u) { return __uint_as_float(u << 16); }
static __device__ inline float bf_hi(unsigned int u) { return __uint_as_float(u & 0xffff0000u); }

static __device__ inline void acc8(float* acc, uint4 u, float w) {
    acc[0] = fmaf(w, bf_lo(u.x), acc[0]);
    acc[1] = fmaf(w, bf_hi(u.x), acc[1]);
    acc[2] = fmaf(w, bf_lo(u.y), acc[2]);
    acc[3] = fmaf(w, bf_hi(u.y), acc[3]);
    acc[4] = fmaf(w, bf_lo(u.z), acc[4]);
    acc[5] = fmaf(w, bf_hi(u.z), acc[5]);
    acc[6] = fmaf(w, bf_lo(u.w), acc[6]);
    acc[7] = fmaf(w, bf_hi(u.w), acc[7]);
}

// ---- fused preprocessing: blocks [0,3125) deg | [3125,9375) x->bf16 |
// ---- [9375,9407) W1 pack | 9407 b1/W2 pad ----
__global__ __launch_bounds__(256) void k_pre(const int* __restrict__ dst,
                                             const float* __restrict__ x,
                                             const float* __restrict__ W1,
                                             const float* __restrict__ b1,
                                             const float* __restrict__ W2,
                                             int* __restrict__ deg,
                                             uint2* __restrict__ x_bf,
                                             unsigned short* __restrict__ b_pk,
                                             float* __restrict__ b1p,
                                             float* __restrict__ w2p) {
    const int b = blockIdx.x, tid = threadIdx.x;
    if (b < 3125) {                                   // deg histogram
        int e = b * 256 + tid;
        atomicAdd(&deg[dst[e]], 1);
    } else if (b < 9375) {                            // x -> bf16 (4 elems/thread)
        int i = (b - 3125) * 256 + tid;               // i < 1,600,000
        float4 v = ((const float4*)x)[i];
        uint2 o;
        o.x = f2bf(v.x) | (f2bf(v.y) << 16);
        o.y = f2bf(v.z) | (f2bf(v.w) << 16);
        x_bf[i] = o;
    } else if (b < 9407) {                            // W1 -> B-fragment pack
        int idx  = (b - 9375) * 256 + tid;            // [0, 8192)
        int lane = idx & 63;
        int slot = idx >> 6;
        int t    = slot >> 2;                         // n-tile
        int ks   = slot & 3;                          // k-step
        int quad = lane >> 4;
        int n    = t * 16 + (lane & 15);
        unsigned int us[8];
#pragma unroll
        for (int j = 0; j < 8; j++) {
            int k = ks * 32 + quad * 8 + j;
            float v = (n < D_HID) ? W1[(size_t)k * D_HID + n] : 0.f;
            us[j] = f2bf(v);
        }
        uint4 p;
        p.x = us[0] | (us[1] << 16);
        p.y = us[2] | (us[3] << 16);
        p.z = us[4] | (us[5] << 16);
        p.w = us[6] | (us[7] << 16);
        ((uint4*)b_pk)[idx] = p;
    } else {                                          // pad b1 / W2 to 512
        for (int i = tid; i < 512; i += 256) {
            b1p[i] = (i < D_HID) ? b1[i] : 0.f;
            w2p[i] = (i < D_HID) ? W2[i] : 0.f;
        }
    }
}

// Single-kernel exclusive scan via decoupled lookback. state[b]: bits[31:30]
// status (1=AGG, 3=INCL), bits[29:0] value (N_EDGES=800000 < 2^30). All 196
// blocks are co-resident (196 < 256 CUs), block 0 always publishes INCL ->
// lookback terminates regardless of dispatch order.
__global__ __launch_bounds__(256) void k_scan(const int* __restrict__ deg,
                                              int* __restrict__ row_ptr,
                                              int* __restrict__ cursor,
                                              float* __restrict__ dinv,
                                              unsigned int* __restrict__ state) {
    __shared__ int ps[256];
    __shared__ int s_prefix;
    const int tid = threadIdx.x;
    const int b = blockIdx.x;
    const int i = b * 256 + tid;
    if (tid == 0) s_prefix = 0;
    int v = (i < N_NODES) ? deg[i] : 0;
    ps[tid] = v;
    __syncthreads();
    for (int off = 1; off < 256; off <<= 1) {
        int t = (tid >= off) ? ps[tid - off] : 0;
        __syncthreads();
        ps[tid] += t;
        __syncthreads();
    }
    const int total = ps[255];

    if (tid == 0) {
        unsigned int st = (b == 0) ? (0xC0000000u | (unsigned)total)
                                   : (0x40000000u | (unsigned)total);
        __hip_atomic_store(&state[b], st, __ATOMIC_RELEASE, __HIP_MEMORY_SCOPE_AGENT);
    }

    if (b > 0 && tid < 64) {                          // wave 0: parallel lookback
        int prefix = 0;
        int look = b - 1;
        while (true) {
            int idx = look - tid;
            unsigned int st = 0xC0000000u;            // idx<0: virtual INCL value 0
            if (idx >= 0)
                st = __hip_atomic_load(&state[idx], __ATOMIC_ACQUIRE,
                                       __HIP_MEMORY_SCOPE_AGENT);
            bool ready = (st >> 30) == 1u || (st >> 30) == 3u;
            if (__ballot(!ready)) continue;           // window not ready, re-poll
            bool incl = (st >> 30) == 3u;
            unsigned long long im = __ballot(incl);
            int contrib;
            if (im == 0ull) {
                contrib = (int)(st & 0x3FFFFFFFu);    // all aggregates, keep walking
            } else {
                int stop = __ffsll(im) - 1;           // lowest lane = highest idx INCL
                contrib = (tid <= stop) ? (int)(st & 0x3FFFFFFFu) : 0;
            }
#pragma unroll
            for (int off = 32; off >= 1; off >>= 1) contrib += __shfl_xor(contrib, off);
            prefix += contrib;
            if (im != 0ull) break;
            look -= 64;
        }
        if (tid == 0) {
            s_prefix = prefix;
            __hip_atomic_store(&state[b], 0xC0000000u | (unsigned)(prefix + total),
                               __ATOMIC_RELEASE, __HIP_MEMORY_SCOPE_AGENT);
        }
    }
    __syncthreads();
    const int bp = s_prefix;
    if (i < N_NODES) {
        int r = bp + ps[tid] - v;                     // exclusive prefix
        row_ptr[i] = r;
        cursor[i] = r;                                // k_fill bumps this copy
        dinv[i] = rsqrtf((float)(v + 1));
    }
    if (b == 0 && tid == 0) row_ptr[N_NODES] = N_EDGES;
}

__global__ __launch_bounds__(256) void k_fill(const int* __restrict__ src,
                                              const int* __restrict__ dst,
                                              int* __restrict__ cursor,
                                              int* __restrict__ csr) {
    int e = blockIdx.x * 256 + threadIdx.x;
    if (e < N_EDGES) {
        int pos = atomicAdd(&cursor[dst[e]], 1);
        csr[pos] = src[e];
    }
}

// Fused gather + bf16-MFMA MLP. Block = 16 nodes, 4 waves; wave gathers 4
// nodes. Row layout: 16 lanes x 16B = 256B row; quarter-wave q handles edge
// e+q -> one dwordx4 instruction fetches 4 rows (1KB).
__global__ __launch_bounds__(256, 4) void k_gcn1(const uint4* __restrict__ xb4,
                                                 const int* __restrict__ csr,
                                                 const int* __restrict__ row_ptr,
                                                 const float* __restrict__ dinv,
                                                 const unsigned short* __restrict__ b_pk,
                                                 const float* __restrict__ b1p,
                                                 const float* __restrict__ w2p,
                                                 float* __restrict__ zd) {
    __shared__ unsigned short A[16][136];   // bf16 rows; 272B stride -> 2-way LDS alias (free)
    __shared__ float red[4][16];
    const int t = threadIdx.x;
    const int node0 = blockIdx.x * 16;      // 50000 = 16 * 3125
    const int wv = t >> 6, lane = t & 63;
    const int q = lane >> 4, p = lane & 15;

    // ---- Phase 1: gather; lane owns bf16 cols [p*8, p*8+8) of quarter-q's edge ----
    for (int nn = 0; nn < 4; nn++) {
        const int n = wv * 4 + nn;
        const int node = node0 + n;
        int e = row_ptr[node];
        const int end = row_ptr[node + 1];
        float acc[8];
#pragma unroll
        for (int j = 0; j < 8; j++) acc[j] = 0.f;

        for (; e + 8 <= end; e += 8) {      // 8 edges in flight per wave
            int s0 = csr[e + q];
            int s1 = csr[e + 4 + q];
            float w0 = dinv[s0];
            float w1 = dinv[s1];
            uint4 u0 = xb4[(size_t)s0 * 16 + p];
            uint4 u1 = xb4[(size_t)s1 * 16 + p];
            acc8(acc, u0, w0);
            acc8(acc, u1, w1);
        }
        for (; e < end; e += 4) {           // predicated tail, 4 at a time
            int idx = e + q;
            bool valid = idx < end;
            int s = valid ? csr[idx] : node;
            float w = valid ? dinv[s] : 0.f;
            uint4 u = xb4[(size_t)s * 16 + p];
            acc8(acc, u, w);
        }
#pragma unroll
        for (int j = 0; j < 8; j++) {       // combine quarter partials
            acc[j] += __shfl_xor(acc[j], 16);
            acc[j] += __shfl_xor(acc[j], 32);
        }
        if (q == 0) {                       // finalize + write row (16 lanes)
            const float di = dinv[node];
            const float dd = di * di;
            uint4 su = xb4[(size_t)node * 16 + p];
            uint4 o;
            o.x = f2bf(di * acc[0] + dd * bf_lo(su.x)) |
                  (f2bf(di * acc[1] + dd * bf_hi(su.x)) << 16);
            o.y = f2bf(di * acc[2] + dd * bf_lo(su.y)) |
                  (f2bf(di * acc[3] + dd * bf_hi(su.y)) << 16);
            o.z = f2bf(di * acc[4] + dd * bf_lo(su.z)) |
                  (f2bf(di * acc[5] + dd * bf_hi(su.z)) << 16);
            o.w = f2bf(di * acc[6] + dd * bf_lo(su.w)) |
                  (f2bf(di * acc[7] + dd * bf_hi(su.w)) << 16);
            *(uint4*)&A[n][p * 8] = o;
        }
    }
    __syncthreads();

    // ---- Phase 2: D[16][512] via 16x16x32 bf16 MFMA; wave owns 8 n-tiles ----
    bf16x8 afr[4];
#pragma unroll
    for (int ks = 0; ks < 4; ks++)
        afr[ks] = *(const bf16x8*)&A[p][ks * 32 + q * 8];

    const bf16x8* __restrict__ bpk = (const bf16x8*)b_pk;
    f32x4 acc[8];
#pragma unroll
    for (int tt = 0; tt < 8; tt++) acc[tt] = (f32x4){0.f, 0.f, 0.f, 0.f};

#pragma unroll
    for (int tt = 0; tt < 8; tt++) {
        const int tile = wv * 8 + tt;
#pragma unroll
        for (int ks = 0; ks < 4; ks++) {
            bf16x8 bfr = bpk[(size_t)(tile * 4 + ks) * 64 + lane];
            acc[tt] = __builtin_amdgcn_mfma_f32_16x16x32_bf16(afr[ks], bfr, acc[tt], 0, 0, 0);
        }
    }

    // epilogue: zd-partial = relu(D + b1) . W2   (C/D: col=p, row=q*4+r)
    float zp[4] = {0.f, 0.f, 0.f, 0.f};
#pragma unroll
    for (int tt = 0; tt < 8; tt++) {
        const int c = (wv * 8 + tt) * 16 + p;
        const float b1v = b1p[c];
        const float w2v = w2p[c];
#pragma unroll
        for (int r = 0; r < 4; r++)
            zp[r] += fmaxf(acc[tt][r] + b1v, 0.f) * w2v;
    }
#pragma unroll
    for (int off = 1; off < 16; off <<= 1) {
#pragma unroll
        for (int r = 0; r < 4; r++) zp[r] += __shfl_xor(zp[r], off);
    }
    if (p == 0) {
#pragma unroll
        for (int r = 0; r < 4; r++) red[wv][q * 4 + r] = zp[r];
    }
    __syncthreads();
    if (t < 16) {
        int node = node0 + t;
        float zz = red[0][t] + red[1][t] + red[2][t] + red[3][t];
        zd[node] = dinv[node] * zz;
    }
}

// Layer-2 scalar gather: 16 lanes per node, shuffle-reduce (zd is 200KB, L2-hot).
__global__ __launch_bounds__(256) void k_gz(const int* __restrict__ csr,
                                            const int* __restrict__ row_ptr,
                                            const float* __restrict__ dinv,
                                            const float* __restrict__ zd,
                                            const float* __restrict__ b2,
                                            float* __restrict__ out) {
    const int node = blockIdx.x * 16 + (threadIdx.x >> 4);
    const int l = threadIdx.x & 15;
    const int start = row_ptr[node], end = row_ptr[node + 1];
    float s = 0.f;
    for (int e = start + l; e < end; e += 16) s += zd[csr[e]];
#pragma unroll
    for (int off = 1; off < 16; off <<= 1) s += __shfl_xor(s, off);
    if (l == 0) out[node] = dinv[node] * (s + zd[node]) + b2[0];
}

extern "C" void kernel_launch(void* const* d_in, const int* in_sizes, int n_in,
                              void* d_out, int out_size, void* d_ws, size_t ws_size,
                              hipStream_t stream) {
    const float* x  = (const float*)d_in[0];
    const int*   ei = (const int*)d_in[1];     // [2, E]: row 0 = src, row 1 = dst
    const float* W1 = (const float*)d_in[2];
    const float* b1 = (const float*)d_in[3];
    const float* W2 = (const float*)d_in[4];
    const float* b2 = (const float*)d_in[5];
    float* out = (float*)d_out;

    const int* src = ei;
    const int* dst = ei + N_EDGES;

    // Workspace layout (~17.5 MB). deg and state adjacent -> one memset.
    uint2* x_bf          = (uint2*)d_ws;                       // 1,600,000 uint2 (12.8 MB)
    unsigned short* b_pk = (unsigned short*)(x_bf + 1600000);  // 65,536 bf16 (128 KB)
    float* b1p    = (float*)(b_pk + 65536);                    // 512
    float* w2p    = b1p + 512;                                 // 512
    float* dinv   = w2p + 512;                                 // 50000
    float* zd     = dinv + N_NODES;                            // 50000
    int* deg      = (int*)(zd + N_NODES);                      // 50000
    unsigned int* state = (unsigned int*)(deg + N_NODES);      // 256
    int* row_ptr  = (int*)(state + 256);                       // 50001
    int* cursor   = row_ptr + N_NODES + 1;                     // 50000
    int* csr      = cursor + N_NODES;                          // 800000

    hipMemsetAsync(deg, 0, (N_NODES + 256) * sizeof(int), stream);

    k_pre <<<9408, 256, 0, stream>>>(dst, x, W1, b1, W2, deg, x_bf, b_pk, b1p, w2p);
    k_scan<<<SCANB, 256, 0, stream>>>(deg, row_ptr, cursor, dinv, state);
    k_fill<<<(N_EDGES + 255) / 256, 256, 0, stream>>>(src, dst, cursor, csr);
    k_gcn1<<<N_NODES / 16, 256, 0, stream>>>((const uint4*)x_bf, csr, row_ptr, dinv,
                                             b_pk, b1p, w2p, zd);
    k_gz  <<<N_NODES / 16, 256, 0, stream>>>(csr, row_ptr, dinv, zd, b2, out);
}